// Round 11
// baseline (415.659 us; speedup 1.0000x reference)
//
#include <hip/hip_runtime.h>
#include <hip/hip_bf16.h>

#define NN 8192
#define FF 64
#define JSPLIT 8
#define JRANGE (NN / JSPLIT)    // 1024 cols per wave-tile
#define PROW 66                 // partial row stride: H[0..63], l at [64]

typedef _Float16 half8 __attribute__((ext_vector_type(8)));
typedef _Float16 half4v __attribute__((ext_vector_type(4)));
typedef _Float16 half2v __attribute__((ext_vector_type(2)));
typedef float f32x4 __attribute__((ext_vector_type(4)));
typedef int i32x4 __attribute__((ext_vector_type(4)));

// ---------------------------------------------------------------------------
// Kernel 0: adj -> bit-mask. Layout: [row][js8][cc2][g4][16B uint4],
// uint4 word w holds bytes it=4w..4w+3; byte it = cols js*1024+it*64+cc*32+g*8.
// Thread = (row, js, cc, g): reads 16 x 32 B, writes one uint4. 1024 B/row.
// ---------------------------------------------------------------------------
__global__ __launch_bounds__(256) void k_pack(const int* __restrict__ adj,
                                              unsigned char* __restrict__ mask2)
{
    const int tid  = threadIdx.x;
    const int row  = blockIdx.x * 4 + (tid >> 6);
    const int lane = tid & 63;
    const int js = lane >> 3, cc = (lane >> 2) & 1, g = lane & 3;
    const int* src = adj + (size_t)row * NN + js * JRANGE + cc * 32 + g * 8;

    unsigned ow[4];
    #pragma unroll
    for (int w = 0; w < 4; ++w) {
        unsigned o = 0;
        #pragma unroll
        for (int h = 0; h < 4; ++h) {
            const int it = w * 4 + h;
            i32x4 a = __builtin_nontemporal_load((const i32x4*)(src + it * 64));
            i32x4 b = __builtin_nontemporal_load((const i32x4*)(src + it * 64 + 4));
            unsigned by = 0;
            by |= (a[0] > 0) ? 1u   : 0u;
            by |= (a[1] > 0) ? 2u   : 0u;
            by |= (a[2] > 0) ? 4u   : 0u;
            by |= (a[3] > 0) ? 8u   : 0u;
            by |= (b[0] > 0) ? 16u  : 0u;
            by |= (b[1] > 0) ? 32u  : 0u;
            by |= (b[2] > 0) ? 64u  : 0u;
            by |= (b[3] > 0) ? 128u : 0u;
            o |= by << (h * 8);
        }
        ow[w] = o;
    }
    uint4 v; v.x = ow[0]; v.y = ow[1]; v.z = ow[2]; v.w = ow[3];
    *(uint4*)(mask2 + (size_t)row * 1024 + js * 128 + cc * 64 + g * 16) = v;
}

// ---------------------------------------------------------------------------
// Kernel 1: Wh = inputs @ W; s, d; WhB in MFMA-B-FRAGMENT PANEL layout:
// for col-panel p (32 cols), n (0..3), mrow (0..15), g (0..3):
//   WhB[((p*4+n)*64 + mrow*4 + g)*8 + e] = Wh[col = p*32+g*8+e][feat = n*16+mrow]
// so one wave b128-load per (panel,n) is 1 KB fully contiguous.
// Also per-block max(d).
// ---------------------------------------------------------------------------
__global__ __launch_bounds__(256) void k_prep(const float* __restrict__ inp,
                                              const float* __restrict__ W,
                                              const float* __restrict__ a,
                                              _Float16* __restrict__ WhB,
                                              float* __restrict__ s,
                                              float* __restrict__ d,
                                              float* __restrict__ dmax_part)
{
    __shared__ float Wl[64][64];
    __shared__ float asrc[64], adst[64];
    __shared__ _Float16 tr[64][20];
    __shared__ float dmx[16];
    const int t = threadIdx.x;
    for (int idx = t; idx < 4096; idx += 256) Wl[idx >> 6][idx & 63] = W[idx];
    if (t < 64) { asrc[t] = a[t]; adst[t] = a[64 + t]; }
    __syncthreads();

    const int rowl = t >> 4;          // row within 16-row block (a "col" of WhB)
    const int fg   = t & 15;
    const int row  = blockIdx.x * 16 + rowl;
    const float* ip = inp + (size_t)row * FF;

    float a0 = 0.f, a1 = 0.f, a2 = 0.f, a3 = 0.f;
    #pragma unroll
    for (int k4 = 0; k4 < 16; ++k4) {
        float4 x  = *(const float4*)(ip + k4 * 4);
        float4 w0 = *(const float4*)&Wl[k4 * 4 + 0][fg * 4];
        float4 w1 = *(const float4*)&Wl[k4 * 4 + 1][fg * 4];
        float4 w2 = *(const float4*)&Wl[k4 * 4 + 2][fg * 4];
        float4 w3 = *(const float4*)&Wl[k4 * 4 + 3][fg * 4];
        a0 += x.x * w0.x + x.y * w1.x + x.z * w2.x + x.w * w3.x;
        a1 += x.x * w0.y + x.y * w1.y + x.z * w2.y + x.w * w3.y;
        a2 += x.x * w0.z + x.y * w1.z + x.z * w2.z + x.w * w3.z;
        a3 += x.x * w0.w + x.y * w1.w + x.z * w2.w + x.w * w3.w;
    }

    float sp = a0 * asrc[fg*4] + a1 * asrc[fg*4+1] + a2 * asrc[fg*4+2] + a3 * asrc[fg*4+3];
    float dp = a0 * adst[fg*4] + a1 * adst[fg*4+1] + a2 * adst[fg*4+2] + a3 * adst[fg*4+3];
    #pragma unroll
    for (int msk = 1; msk < 16; msk <<= 1) {
        sp += __shfl_xor(sp, msk);
        dp += __shfl_xor(dp, msk);
    }
    if (fg == 0) { s[row] = sp; d[row] = dp; dmx[rowl] = dp; }

    tr[fg * 4 + 0][rowl] = (_Float16)a0;
    tr[fg * 4 + 1][rowl] = (_Float16)a1;
    tr[fg * 4 + 2][rowl] = (_Float16)a2;
    tr[fg * 4 + 3][rowl] = (_Float16)a3;
    __syncthreads();
    {
        // thread (f, seg): cols j = blockIdx*16 + seg*4 .. +3, feature f
        const int f = t >> 2, seg = t & 3;
        const int n = f >> 4, mr = f & 15;
        const int jb = blockIdx.x * 16 + seg * 4;   // multiple of 4
        const int p  = jb >> 5;
        const int g  = (jb >> 3) & 3;
        const int e  = jb & 7;                      // 0 or 4
        *(half4v*)(WhB + ((size_t)(p * 4 + n) * 64 + mr * 4 + g) * 8 + e) =
            *(const half4v*)&tr[f][seg * 4];
    }
    if (t == 0) {
        float mm = dmx[0];
        #pragma unroll
        for (int i = 1; i < 16; ++i) mm = fmaxf(mm, dmx[i]);
        dmax_part[blockIdx.x] = mm;
    }
}

// ---------------------------------------------------------------------------
// Kernel 2: dmax; separable softmax factors (all <= 1, fp16-safe).
// ---------------------------------------------------------------------------
__global__ __launch_bounds__(256) void k_vec(const float* __restrict__ s,
                                             const float* __restrict__ d,
                                             const float* __restrict__ dmax_part,
                                             _Float16* __restrict__ afac,
                                             _Float16* __restrict__ cfac,
                                             _Float16* __restrict__ bfac,
                                             _Float16* __restrict__ dfac)
{
    __shared__ float red[256];
    const int t = threadIdx.x;
    float m = fmaxf(dmax_part[t], dmax_part[t + 256]);
    red[t] = m;
    __syncthreads();
    for (int off = 128; off > 0; off >>= 1) {
        if (t < off) red[t] = fmaxf(red[t], red[t + off]);
        __syncthreads();
    }
    const float dmax = red[0];
    const int row = blockIdx.x * 256 + t;
    const float x = s[row] + dmax;
    const float c = fmaxf(x, 0.2f * x);
    afac[row] = (_Float16)__expf(x - c);
    cfac[row] = (_Float16)__expf(0.2f * x - c);
    const float y = d[row] - dmax;
    bfac[row] = (_Float16)__expf(y);
    dfac[row] = (_Float16)__expf(0.2f * y);
}

// ---------------------------------------------------------------------------
// Kernel 3 (main): 4096 INDEPENDENT wave-tiles (1024 blocks x 4 waves), each
// 16 rows x 1024 cols. NO LDS, NO barriers, no waitcnt fences. Bit-mask in
// VGPRs (one uint4 pair), B via fully-coalesced 1KB b128 panel loads
// (L1/L2-hot; waves sharing js read identical lines), factors via 16B
// broadcast loads. 32 fully-unrolled chunks; compiler pipelines freely.
// ---------------------------------------------------------------------------
__global__ __launch_bounds__(256, 4) void k_main(const unsigned char* __restrict__ mask2,
                                                 const _Float16* __restrict__ WhB,
                                                 const _Float16* __restrict__ afac,
                                                 const _Float16* __restrict__ cfac,
                                                 const _Float16* __restrict__ bfac,
                                                 const _Float16* __restrict__ dfac,
                                                 float* __restrict__ part)
{
    const int tid  = threadIdx.x;
    const int wv   = tid >> 6;
    const int lane = tid & 63;
    const int mrow = lane & 15;
    const int g    = lane >> 4;
    const int w    = blockIdx.x * 4 + wv;     // 0..4095
    const int rg   = w & 511;                 // row-group (16 rows)
    const int js   = w >> 9;                  // column window
    const int arow = rg * 16 + mrow;
    const int j0   = js * JRANGE;

    // ---- per-lane bit-mask: 2 x uint4 (cc=0,1), straight to VGPRs
    const unsigned char* mb = mask2 + (size_t)arow * 1024 + js * 128 + g * 16;
    uint4 mk0 = *(const uint4*)(mb);
    uint4 mk1 = *(const uint4*)(mb + 64);

    // ---- per-row factors (packed fp16 pairs, lane-uniform per row)
    union { _Float16 h[2]; half2v v; } u;
    u.h[0] = afac[arow]; u.h[1] = u.h[0]; const half2v a2 = u.v;
    u.h[0] = cfac[arow]; u.h[1] = u.h[0]; const half2v c2 = u.v;

    f32x4 acc[5];
    #pragma unroll
    for (int n = 0; n < 5; ++n) acc[n] = (f32x4){0.f, 0.f, 0.f, 0.f};

    const half8 ones = {(_Float16)1.f, (_Float16)1.f, (_Float16)1.f, (_Float16)1.f,
                        (_Float16)1.f, (_Float16)1.f, (_Float16)1.f, (_Float16)1.f};

    #pragma unroll
    for (int it = 0; it < 16; ++it) {
        #pragma unroll
        for (int cc = 0; cc < 2; ++cc) {
            const unsigned word = cc ? (&mk1.x)[it >> 2] : (&mk0.x)[it >> 2];
            const unsigned bt   = (word >> ((it & 3) * 8)) & 0xffu;

            const int jc = j0 + it * 64 + cc * 32;            // chunk col base
            uint4 bv4 = *(const uint4*)(bfac + jc + g * 8);   // 16B, bcast x16
            uint4 dv4 = *(const uint4*)(dfac + jc + g * 8);

            union { unsigned u[4]; half8 h; } af;
            #pragma unroll
            for (int k = 0; k < 4; ++k) {
                union { unsigned u; half2v v; } b2, d2, pm;
                b2.u = (&bv4.x)[k];
                d2.u = (&dv4.x)[k];
                pm.v = __builtin_elementwise_max(a2 * b2.v, c2 * d2.v);
                const unsigned lo = ((bt >> (2 * k)) & 1u) * 0xFFFFu;
                const unsigned hi = ((bt >> (2 * k + 1)) & 1u) * 0xFFFF0000u;
                af.u[k] = pm.u & (lo | hi);
            }

            const int p = js * 32 + it * 2 + cc;              // global panel
            #pragma unroll
            for (int n = 0; n < 4; ++n) {
                const half8 B = *(const half8*)(WhB +
                    ((size_t)(p * 4 + n) * 64 + mrow * 4 + g) * 8);
                acc[n] = __builtin_amdgcn_mfma_f32_16x16x32_f16(af.h, B, acc[n], 0, 0, 0);
            }
            acc[4] = __builtin_amdgcn_mfma_f32_16x16x32_f16(af.h, ones, acc[4], 0, 0, 0);
        }
    }

    // ---- epilogue: partial for this wave-tile ----
    float* pb = part + (size_t)w * (16 * PROW);
    #pragma unroll
    for (int n = 0; n < 4; ++n)
        #pragma unroll
        for (int r = 0; r < 4; ++r)
            pb[(g * 4 + r) * PROW + n * 16 + mrow] = acc[n][r];
    if (mrow == 0) {
        #pragma unroll
        for (int r = 0; r < 4; ++r)
            pb[(g * 4 + r) * PROW + 64] = acc[4][r];
    }
}

// ---------------------------------------------------------------------------
// Kernel 4: combine 8 j-split partials, divide by l, ELU, write out.
// part layout: wave-tile w = js*512 + rg -> [16][PROW].
// ---------------------------------------------------------------------------
__global__ __launch_bounds__(256) void k_reduce(const float* __restrict__ part,
                                                float* __restrict__ out)
{
    const int rb  = blockIdx.x;
    const int col = threadIdx.x & 63;
    const int r0  = threadIdx.x >> 6;
    #pragma unroll
    for (int rr = 0; rr < 4; ++rr) {
        const int r  = rb * 16 + r0 * 4 + rr;
        const int rg = r >> 4;
        const int rl = r & 15;
        float h = 0.f, l = 0.f;
        #pragma unroll
        for (int js = 0; js < JSPLIT; ++js) {
            const float* pbase =
                part + ((size_t)(js * 512 + rg) * 16 + rl) * PROW;
            h += pbase[col];
            l += pbase[64];
        }
        float v = h / l;
        out[(size_t)r * FF + col] = (v > 0.f) ? v : (__expf(v) - 1.0f);
    }
}

extern "C" void kernel_launch(void* const* d_in, const int* in_sizes, int n_in,
                              void* d_out, int out_size, void* d_ws, size_t ws_size,
                              hipStream_t stream)
{
    const float* inp = (const float*)d_in[0];
    const int*   adj = (const int*)d_in[1];
    const float* W   = (const float*)d_in[2];
    const float* a   = (const float*)d_in[3];
    float* out = (float*)d_out;

    char* ws = (char*)d_ws;
    _Float16* WhB = (_Float16*)ws;                          // 1 MB (panel layout)
    float* s    = (float*)(ws + (size_t)80 * NN * 2);
    float* d    = s + NN;
    float* dmp  = d + NN;
    _Float16* afac = (_Float16*)(dmp + 512);
    _Float16* cfac = afac + NN;
    _Float16* bfac = cfac + NN;
    _Float16* dfac = bfac + NN;
    float* part = (float*)(dfac + NN);                      // 4096*16*66*4 = 17.3 MB
    unsigned char* mask2 = (unsigned char*)(part + (size_t)4096 * 16 * PROW);  // 8 MB

    k_pack  <<<NN / 4, 256, 0, stream>>>(adj, mask2);
    k_prep  <<<NN / 16, 256, 0, stream>>>(inp, W, a, WhB, s, d, dmp);
    k_vec   <<<NN / 256, 256, 0, stream>>>(s, d, dmp, afac, cfac, bfac, dfac);
    k_main  <<<1024, 256, 0, stream>>>(mask2, WhB, afac, cfac, bfac, dfac, part);
    k_reduce<<<NN / 16, 256, 0, stream>>>(part, out);
}

// Round 12
// 394.960 us; speedup vs baseline: 1.0524x; 1.0524x over previous
//
#include <hip/hip_runtime.h>
#include <hip/hip_bf16.h>

#define NN 8192
#define FF 64
#define JSPLIT 16
#define JRANGE (NN / JSPLIT)    // 512 cols per block
#define JT 64                   // cols per iteration
#define NIT (JRANGE / JT)       // 8
#define PROW 66                 // partial row stride: H[0..63], l at [64]

// LDS (bytes): 4 B-buffers + factor window = 36864. The adj-transpose
// scratch (256 x 36 = 9216 B) aliases the B-buffer area (prologue only).
#define B_OFF   0
#define FAC_OFF 32768
#define LDS_SZ  36864

typedef _Float16 half8 __attribute__((ext_vector_type(8)));
typedef _Float16 half4v __attribute__((ext_vector_type(4)));
typedef _Float16 half2v __attribute__((ext_vector_type(2)));
typedef float f32x4 __attribute__((ext_vector_type(4)));
typedef int i32x4 __attribute__((ext_vector_type(4)));

__device__ __forceinline__ void async16(const void* g, void* l)
{
    __builtin_amdgcn_global_load_lds(
        (const __attribute__((address_space(1))) unsigned int*)g,
        (__attribute__((address_space(3))) unsigned int*)l, 16, 0, 0);
}

// ---------------------------------------------------------------------------
// Kernel 1: Wh = inputs @ W; s, d; WhT fp16 (64 x NN); per-block max(d).
// ---------------------------------------------------------------------------
__global__ __launch_bounds__(256) void k_prep(const float* __restrict__ inp,
                                              const float* __restrict__ W,
                                              const float* __restrict__ a,
                                              _Float16* __restrict__ WhT,
                                              float* __restrict__ s,
                                              float* __restrict__ d,
                                              float* __restrict__ dmax_part)
{
    __shared__ float Wl[64][64];
    __shared__ float asrc[64], adst[64];
    __shared__ _Float16 tr[64][20];
    __shared__ float dmx[16];
    const int t = threadIdx.x;
    for (int idx = t; idx < 4096; idx += 256) Wl[idx >> 6][idx & 63] = W[idx];
    if (t < 64) { asrc[t] = a[t]; adst[t] = a[64 + t]; }
    __syncthreads();

    const int rowl = t >> 4;
    const int fg   = t & 15;
    const int row  = blockIdx.x * 16 + rowl;
    const float* ip = inp + (size_t)row * FF;

    float a0 = 0.f, a1 = 0.f, a2 = 0.f, a3 = 0.f;
    #pragma unroll
    for (int k4 = 0; k4 < 16; ++k4) {
        float4 x  = *(const float4*)(ip + k4 * 4);
        float4 w0 = *(const float4*)&Wl[k4 * 4 + 0][fg * 4];
        float4 w1 = *(const float4*)&Wl[k4 * 4 + 1][fg * 4];
        float4 w2 = *(const float4*)&Wl[k4 * 4 + 2][fg * 4];
        float4 w3 = *(const float4*)&Wl[k4 * 4 + 3][fg * 4];
        a0 += x.x * w0.x + x.y * w1.x + x.z * w2.x + x.w * w3.x;
        a1 += x.x * w0.y + x.y * w1.y + x.z * w2.y + x.w * w3.y;
        a2 += x.x * w0.z + x.y * w1.z + x.z * w2.z + x.w * w3.z;
        a3 += x.x * w0.w + x.y * w1.w + x.z * w2.w + x.w * w3.w;
    }

    float sp = a0 * asrc[fg*4] + a1 * asrc[fg*4+1] + a2 * asrc[fg*4+2] + a3 * asrc[fg*4+3];
    float dp = a0 * adst[fg*4] + a1 * adst[fg*4+1] + a2 * adst[fg*4+2] + a3 * adst[fg*4+3];
    #pragma unroll
    for (int msk = 1; msk < 16; msk <<= 1) {
        sp += __shfl_xor(sp, msk);
        dp += __shfl_xor(dp, msk);
    }
    if (fg == 0) { s[row] = sp; d[row] = dp; dmx[rowl] = dp; }

    tr[fg * 4 + 0][rowl] = (_Float16)a0;
    tr[fg * 4 + 1][rowl] = (_Float16)a1;
    tr[fg * 4 + 2][rowl] = (_Float16)a2;
    tr[fg * 4 + 3][rowl] = (_Float16)a3;
    __syncthreads();
    {
        const int f = t >> 2, seg = t & 3;
        *(half4v*)(WhT + (size_t)f * NN + blockIdx.x * 16 + seg * 4) =
            *(const half4v*)&tr[f][seg * 4];
    }
    if (t == 0) {
        float mm = dmx[0];
        #pragma unroll
        for (int i = 1; i < 16; ++i) mm = fmaxf(mm, dmx[i]);
        dmax_part[blockIdx.x] = mm;
    }
}

// ---------------------------------------------------------------------------
// Kernel 2: dmax; separable softmax factors (all <= 1, fp16-safe).
// ---------------------------------------------------------------------------
__global__ __launch_bounds__(256) void k_vec(const float* __restrict__ s,
                                             const float* __restrict__ d,
                                             const float* __restrict__ dmax_part,
                                             _Float16* __restrict__ afac,
                                             _Float16* __restrict__ cfac,
                                             _Float16* __restrict__ bfac,
                                             _Float16* __restrict__ dfac)
{
    __shared__ float red[256];
    const int t = threadIdx.x;
    float m = fmaxf(dmax_part[t], dmax_part[t + 256]);
    red[t] = m;
    __syncthreads();
    for (int off = 128; off > 0; off >>= 1) {
        if (t < off) red[t] = fmaxf(red[t], red[t + off]);
        __syncthreads();
    }
    const float dmax = red[0];
    const int row = blockIdx.x * 256 + t;
    const float x = s[row] + dmax;
    const float c = fmaxf(x, 0.2f * x);
    afac[row] = (_Float16)__expf(x - c);
    cfac[row] = (_Float16)__expf(0.2f * x - c);
    const float y = d[row] - dmax;
    bfac[row] = (_Float16)__expf(y);
    dfac[row] = (_Float16)__expf(0.2f * y);
}

// ---------------------------------------------------------------------------
// Kernel 3 (main, merged pack): 1024 blocks = 64 row-tiles(128) x 16 j-splits.
// PROLOGUE: block reads its 128x512 adj sub-matrix fully coalesced (64 int4
// steps = 2 complete rows/step), bit-packs in VGPRs, transposes via 9 KB LDS
// scratch into per-lane mask words. LOOP: identical to R10 (4 B-buffers,
// vmcnt(2) prefetch distance 2, one s_barrier/iter, separable factors, no
// exp, 2 A-frags/wave).
// ---------------------------------------------------------------------------
__global__ __launch_bounds__(256, 4) void k_main(const int* __restrict__ adj,
                                                 const _Float16* __restrict__ WhT,
                                                 const _Float16* __restrict__ afac,
                                                 const _Float16* __restrict__ cfac,
                                                 const _Float16* __restrict__ bfac,
                                                 const _Float16* __restrict__ dfac,
                                                 float* __restrict__ part)
{
    __shared__ __align__(16) unsigned char sm[LDS_SZ];

    const int tid  = threadIdx.x;
    const int wv   = tid >> 6;
    const int lane = tid & 63;
    const int mrow = lane & 15;
    const int g    = lane >> 4;
    const int rt   = blockIdx.x & 63;
    const int js   = blockIdx.x >> 6;
    const int i0   = rt * 128;
    const int j0base = js * JRANGE;
    const int arow0 = i0 + wv * 32 + mrow;
    const int arow1 = arow0 + 16;

    // ================= PROLOGUE: adj stream -> per-lane mask words =========
    // Phase 1: coalesced read + nibble pack. Thread (hi=tid>>7, pc=tid&127):
    // step i covers rows {2i+hi}, cols j0base + pc*4 .. +3.
    unsigned nw[8];
    #pragma unroll
    for (int w = 0; w < 8; ++w) nw[w] = 0;
    {
        const int prow_hi = tid >> 7;
        const int pc      = tid & 127;
        const int* asrc = adj + (size_t)(i0 + prow_hi) * NN + j0base + pc * 4;
        #pragma unroll 8
        for (int i = 0; i < 64; ++i) {
            i32x4 v = __builtin_nontemporal_load(
                (const i32x4*)(asrc + (size_t)i * 2 * NN));
            unsigned nib = (v[0] > 0 ? 1u : 0u) | (v[1] > 0 ? 2u : 0u) |
                           (v[2] > 0 ? 4u : 0u) | (v[3] > 0 ? 8u : 0u);
            nw[i >> 3] |= nib << ((i & 7) * 4);
        }
    }
    // Phase 2: blob to LDS scratch (stride 36 to spread banks)
    {
        const int prow_hi = tid >> 7;
        const int pc      = tid & 127;
        unsigned char* nb = &sm[(pc * 2 + prow_hi) * 36];
        #pragma unroll
        for (int w = 0; w < 8; ++w)
            *(unsigned*)(nb + w * 4) = nw[w];
    }
    __syncthreads();
    // Phase 3: gather this lane's mask words.
    // Row r: hi=r&1, word wsel=(r>>1)>>3 = wv*2+rr, shift ((r>>1)&7)*4.
    // Chunk (it,cc): nibble cols c0=it*16+cc*8+g*2 (lo) and c0+1 (hi nibble).
    uint2 mw[2][2];
    {
        const int hi = mrow & 1;
        const int sh = ((mrow >> 1) & 7) * 4;
        #pragma unroll
        for (int rr = 0; rr < 2; ++rr) {
            const int wsel = wv * 2 + rr;
            #pragma unroll
            for (int cc = 0; cc < 2; ++cc) {
                unsigned wlo = 0, whi = 0;
                #pragma unroll
                for (int it = 0; it < 8; ++it) {
                    const int c0 = it * 16 + cc * 8 + g * 2;
                    unsigned n0 = *(const unsigned*)&sm[(c0 * 2 + hi) * 36 + wsel * 4];
                    unsigned n1 = *(const unsigned*)&sm[((c0 + 1) * 2 + hi) * 36 + wsel * 4];
                    const unsigned byte = ((n0 >> sh) & 0xFu) | (((n1 >> sh) & 0xFu) << 4);
                    if (it < 4) wlo |= byte << (it * 8);
                    else        whi |= byte << ((it - 4) * 8);
                }
                mw[rr][cc].x = wlo;
                mw[rr][cc].y = whi;
            }
        }
    }
    __syncthreads();   // scratch reads done before B staging overwrites it

    // ================= R10 pipelined GEMM loop ============================
    half2v a2[2], c2[2];
    {
        union { _Float16 h[2]; half2v v; } u;
        u.h[0] = afac[arow0]; u.h[1] = u.h[0]; a2[0] = u.v;
        u.h[0] = cfac[arow0]; u.h[1] = u.h[0]; c2[0] = u.v;
        u.h[0] = afac[arow1]; u.h[1] = u.h[0]; a2[1] = u.v;
        u.h[0] = cfac[arow1]; u.h[1] = u.h[0]; c2[1] = u.v;
    }

    f32x4 acc[2][5];
    #pragma unroll
    for (int r = 0; r < 2; ++r)
        #pragma unroll
        for (int n = 0; n < 5; ++n) acc[r][n] = (f32x4){0.f, 0.f, 0.f, 0.f};

    auto stageB = [&](int it) {
        const int j0 = j0base + it * JT;
        unsigned char* base = &sm[B_OFF + (it & 3) * 8192];
        #pragma unroll
        for (int qq = 0; qq < 2; ++qq) {
            const int q  = wv * 2 + qq;
            const int f  = q * 8 + (lane >> 3);
            const int sw = (lane & 7) ^ (lane >> 3);
            async16(WhT + (size_t)f * NN + j0 + sw * 8,
                    base + q * 1024 + lane * 16);
        }
    };

    {   // factor window: exactly 1 async16 per wave (uniform vmcnt count)
        const _Float16* fsrc = (wv == 0) ? (bfac + j0base + lane * 8)
                             : (wv == 1) ? (dfac + j0base + lane * 8)
                             : (wv == 2) ? (bfac + j0base + lane * 8)
                                         : (dfac + j0base + lane * 8);
        const int dst = (wv == 0) ? 0 : (wv == 1) ? 1024 : 2048 + (wv - 2) * 1024;
        async16(fsrc, &sm[FAC_OFF + dst + lane * 16]);
    }
    stageB(0);
    stageB(1);

    const half8 ones = {(_Float16)1.f, (_Float16)1.f, (_Float16)1.f, (_Float16)1.f,
                        (_Float16)1.f, (_Float16)1.f, (_Float16)1.f, (_Float16)1.f};
    const int r7 = mrow & 7;
    const int qh = mrow >> 3;

    #pragma unroll
    for (int it = 0; it < NIT; ++it) {
        if (it < NIT - 1)
            asm volatile("s_waitcnt vmcnt(2)" ::: "memory");
        else
            asm volatile("s_waitcnt vmcnt(0)" ::: "memory");
        __builtin_amdgcn_s_barrier();
        asm volatile("" ::: "memory");

        if (it + 2 < NIT) stageB(it + 2);

        const unsigned char* bb = &sm[B_OFF + (it & 3) * 8192];

        #pragma unroll
        for (int cc = 0; cc < 2; ++cc) {
            const int colb = (it * 64 + cc * 32 + g * 8) * 2;
            uint4 bv4 = *(const uint4*)&sm[FAC_OFF + colb];
            uint4 dv4 = *(const uint4*)&sm[FAC_OFF + 1024 + colb];

            union { unsigned u[4]; half8 h; } af[2];
            #pragma unroll
            for (int r = 0; r < 2; ++r) {
                const unsigned w  = (it < 4) ? mw[r][cc].x : mw[r][cc].y;
                const unsigned bt = (w >> ((it & 3) * 8)) & 0xffu;
                #pragma unroll
                for (int k = 0; k < 4; ++k) {
                    union { unsigned u; half2v v; } b2, d2, pm;
                    b2.u = (&bv4.x)[k];
                    d2.u = (&dv4.x)[k];
                    pm.v = __builtin_elementwise_max(a2[r] * b2.v, c2[r] * d2.v);
                    const unsigned lo = ((bt >> (2 * k)) & 1u) * 0xFFFFu;
                    const unsigned hi = ((bt >> (2 * k + 1)) & 1u) * 0xFFFF0000u;
                    af[r].u[k] = pm.u & (lo | hi);
                }
            }

            #pragma unroll
            for (int n = 0; n < 4; ++n) {
                const int q = n * 2 + qh;
                half8 B = *(const half8*)&bb[q * 1024 + r7 * 128 +
                                             (((cc * 4 + g) ^ r7) * 16)];
                acc[0][n] = __builtin_amdgcn_mfma_f32_16x16x32_f16(af[0].h, B, acc[0][n], 0, 0, 0);
                acc[1][n] = __builtin_amdgcn_mfma_f32_16x16x32_f16(af[1].h, B, acc[1][n], 0, 0, 0);
            }
            acc[0][4] = __builtin_amdgcn_mfma_f32_16x16x32_f16(af[0].h, ones, acc[0][4], 0, 0, 0);
            acc[1][4] = __builtin_amdgcn_mfma_f32_16x16x32_f16(af[1].h, ones, acc[1][4], 0, 0, 0);
        }
    }

    // ---- epilogue ----
    float* pb = part + (size_t)blockIdx.x * (128 * PROW) + wv * 32 * PROW;
    #pragma unroll
    for (int r = 0; r < 2; ++r) {
        #pragma unroll
        for (int n = 0; n < 4; ++n)
            #pragma unroll
            for (int reg = 0; reg < 4; ++reg)
                pb[(r * 16 + g * 4 + reg) * PROW + n * 16 + mrow] = acc[r][n][reg];
        if (mrow == 0) {
            #pragma unroll
            for (int reg = 0; reg < 4; ++reg)
                pb[(r * 16 + g * 4 + reg) * PROW + 64] = acc[r][4][reg];
        }
    }
}

// ---------------------------------------------------------------------------
// Kernel 4: combine 16 j-split partials, divide by l, ELU, write out.
// ---------------------------------------------------------------------------
__global__ __launch_bounds__(256) void k_reduce(const float* __restrict__ part,
                                                float* __restrict__ out)
{
    const int rb  = blockIdx.x;
    const int col = threadIdx.x & 63;
    const int r0  = threadIdx.x >> 6;
    #pragma unroll
    for (int rr = 0; rr < 4; ++rr) {
        const int r   = rb * 16 + r0 * 4 + rr;
        const int rtr = r >> 7;
        const int rl  = r & 127;
        float h = 0.f, l = 0.f;
        #pragma unroll
        for (int js = 0; js < JSPLIT; ++js) {
            const float* pbase =
                part + ((size_t)(js * 64 + rtr) * 128 + rl) * PROW;
            h += pbase[col];
            l += pbase[64];
        }
        float v = h / l;
        out[(size_t)r * FF + col] = (v > 0.f) ? v : (__expf(v) - 1.0f);
    }
}

extern "C" void kernel_launch(void* const* d_in, const int* in_sizes, int n_in,
                              void* d_out, int out_size, void* d_ws, size_t ws_size,
                              hipStream_t stream)
{
    const float* inp = (const float*)d_in[0];
    const int*   adj = (const int*)d_in[1];
    const float* W   = (const float*)d_in[2];
    const float* a   = (const float*)d_in[3];
    float* out = (float*)d_out;

    char* ws = (char*)d_ws;
    _Float16* WhT = (_Float16*)ws;                          // 80*NN*2 reserved
    float* s    = (float*)(ws + (size_t)80 * NN * 2);
    float* d    = s + NN;
    float* dmp  = d + NN;
    _Float16* afac = (_Float16*)(dmp + 512);
    _Float16* cfac = afac + NN;
    _Float16* bfac = cfac + NN;
    _Float16* dfac = bfac + NN;
    float* part = (float*)(dfac + NN);                      // 1024*128*66*4 = 34.6 MB

    k_prep  <<<NN / 16, 256, 0, stream>>>(inp, W, a, WhT, s, d, dmp);
    k_vec   <<<NN / 256, 256, 0, stream>>>(s, d, dmp, afac, cfac, bfac, dfac);
    k_main  <<<64 * JSPLIT, 256, 0, stream>>>(adj, WhT, afac, cfac, bfac, dfac, part);
    k_reduce<<<NN / 16, 256, 0, stream>>>(part, out);
}

// Round 13
// 388.782 us; speedup vs baseline: 1.0691x; 1.0159x over previous
//
#include <hip/hip_runtime.h>
#include <hip/hip_bf16.h>

#define NN 8192
#define FF 64
#define JSPLIT 16
#define JRANGE (NN / JSPLIT)    // 512 cols per block
#define JT 64                   // cols per iteration
#define NIT (JRANGE / JT)       // 8
#define PROW 66                 // partial row stride: H[0..63], l at [64]

// LDS (bytes): 2 B-buffers (16 KB) + factor window (4 KB) = 20480 -> 6 blocks/CU
#define B_OFF   0
#define FAC_OFF 16384
#define LDS_SZ  20480

typedef _Float16 half8 __attribute__((ext_vector_type(8)));
typedef _Float16 half4v __attribute__((ext_vector_type(4)));
typedef _Float16 half2v __attribute__((ext_vector_type(2)));
typedef float f32x4 __attribute__((ext_vector_type(4)));
typedef int i32x4 __attribute__((ext_vector_type(4)));

__device__ __forceinline__ void async16(const void* g, void* l)
{
    __builtin_amdgcn_global_load_lds(
        (const __attribute__((address_space(1))) unsigned int*)g,
        (__attribute__((address_space(3))) unsigned int*)l, 16, 0, 0);
}

// ---------------------------------------------------------------------------
// Kernel 0: adj -> bit-mask, layout mask2[row][js16][cc2][g4] (uint2 each,
// byte h of word = iter 4w+h). 1024 B/row. Pure streaming.
// ---------------------------------------------------------------------------
__global__ __launch_bounds__(256) void k_pack(const int* __restrict__ adj,
                                              unsigned char* __restrict__ mask2)
{
    const int tid = threadIdx.x;
    const int row = blockIdx.x * 2 + (tid >> 7);
    const int l7  = tid & 127;
    const int js = l7 >> 3, cc = (l7 >> 2) & 1, g = l7 & 3;
    const int* src = adj + (size_t)row * NN + js * JRANGE + cc * 32 + g * 8;

    unsigned ow[2];
    #pragma unroll
    for (int w = 0; w < 2; ++w) {
        unsigned o = 0;
        #pragma unroll
        for (int h = 0; h < 4; ++h) {
            const int it = w * 4 + h;
            i32x4 a = __builtin_nontemporal_load((const i32x4*)(src + it * 64));
            i32x4 b = __builtin_nontemporal_load((const i32x4*)(src + it * 64 + 4));
            unsigned by = 0;
            by |= (a[0] > 0) ? 1u   : 0u;
            by |= (a[1] > 0) ? 2u   : 0u;
            by |= (a[2] > 0) ? 4u   : 0u;
            by |= (a[3] > 0) ? 8u   : 0u;
            by |= (b[0] > 0) ? 16u  : 0u;
            by |= (b[1] > 0) ? 32u  : 0u;
            by |= (b[2] > 0) ? 64u  : 0u;
            by |= (b[3] > 0) ? 128u : 0u;
            o |= by << (h * 8);
        }
        ow[w] = o;
    }
    uint2 v; v.x = ow[0]; v.y = ow[1];
    *(uint2*)(mask2 + (size_t)row * 1024 + js * 64 + cc * 32 + g * 8) = v;
}

// ---------------------------------------------------------------------------
// Kernel 1: Wh = inputs @ W; s, d; WhT fp16 (64 x NN); per-block max(d).
// ---------------------------------------------------------------------------
__global__ __launch_bounds__(256) void k_prep(const float* __restrict__ inp,
                                              const float* __restrict__ W,
                                              const float* __restrict__ a,
                                              _Float16* __restrict__ WhT,
                                              float* __restrict__ s,
                                              float* __restrict__ d,
                                              float* __restrict__ dmax_part)
{
    __shared__ float Wl[64][64];
    __shared__ float asrc[64], adst[64];
    __shared__ _Float16 tr[64][20];
    __shared__ float dmx[16];
    const int t = threadIdx.x;
    for (int idx = t; idx < 4096; idx += 256) Wl[idx >> 6][idx & 63] = W[idx];
    if (t < 64) { asrc[t] = a[t]; adst[t] = a[64 + t]; }
    __syncthreads();

    const int rowl = t >> 4;
    const int fg   = t & 15;
    const int row  = blockIdx.x * 16 + rowl;
    const float* ip = inp + (size_t)row * FF;

    float a0 = 0.f, a1 = 0.f, a2 = 0.f, a3 = 0.f;
    #pragma unroll
    for (int k4 = 0; k4 < 16; ++k4) {
        float4 x  = *(const float4*)(ip + k4 * 4);
        float4 w0 = *(const float4*)&Wl[k4 * 4 + 0][fg * 4];
        float4 w1 = *(const float4*)&Wl[k4 * 4 + 1][fg * 4];
        float4 w2 = *(const float4*)&Wl[k4 * 4 + 2][fg * 4];
        float4 w3 = *(const float4*)&Wl[k4 * 4 + 3][fg * 4];
        a0 += x.x * w0.x + x.y * w1.x + x.z * w2.x + x.w * w3.x;
        a1 += x.x * w0.y + x.y * w1.y + x.z * w2.y + x.w * w3.y;
        a2 += x.x * w0.z + x.y * w1.z + x.z * w2.z + x.w * w3.z;
        a3 += x.x * w0.w + x.y * w1.w + x.z * w2.w + x.w * w3.w;
    }

    float sp = a0 * asrc[fg*4] + a1 * asrc[fg*4+1] + a2 * asrc[fg*4+2] + a3 * asrc[fg*4+3];
    float dp = a0 * adst[fg*4] + a1 * adst[fg*4+1] + a2 * adst[fg*4+2] + a3 * adst[fg*4+3];
    #pragma unroll
    for (int msk = 1; msk < 16; msk <<= 1) {
        sp += __shfl_xor(sp, msk);
        dp += __shfl_xor(dp, msk);
    }
    if (fg == 0) { s[row] = sp; d[row] = dp; dmx[rowl] = dp; }

    tr[fg * 4 + 0][rowl] = (_Float16)a0;
    tr[fg * 4 + 1][rowl] = (_Float16)a1;
    tr[fg * 4 + 2][rowl] = (_Float16)a2;
    tr[fg * 4 + 3][rowl] = (_Float16)a3;
    __syncthreads();
    {
        const int f = t >> 2, seg = t & 3;
        *(half4v*)(WhT + (size_t)f * NN + blockIdx.x * 16 + seg * 4) =
            *(const half4v*)&tr[f][seg * 4];
    }
    if (t == 0) {
        float mm = dmx[0];
        #pragma unroll
        for (int i = 1; i < 16; ++i) mm = fmaxf(mm, dmx[i]);
        dmax_part[blockIdx.x] = mm;
    }
}

// ---------------------------------------------------------------------------
// Kernel 2: dmax; separable softmax factors (all <= 1, fp16-safe).
// ---------------------------------------------------------------------------
__global__ __launch_bounds__(256) void k_vec(const float* __restrict__ s,
                                             const float* __restrict__ d,
                                             const float* __restrict__ dmax_part,
                                             _Float16* __restrict__ afac,
                                             _Float16* __restrict__ cfac,
                                             _Float16* __restrict__ bfac,
                                             _Float16* __restrict__ dfac)
{
    __shared__ float red[256];
    const int t = threadIdx.x;
    float m = fmaxf(dmax_part[t], dmax_part[t + 256]);
    red[t] = m;
    __syncthreads();
    for (int off = 128; off > 0; off >>= 1) {
        if (t < off) red[t] = fmaxf(red[t], red[t + off]);
        __syncthreads();
    }
    const float dmax = red[0];
    const int row = blockIdx.x * 256 + t;
    const float x = s[row] + dmax;
    const float c = fmaxf(x, 0.2f * x);
    afac[row] = (_Float16)__expf(x - c);
    cfac[row] = (_Float16)__expf(0.2f * x - c);
    const float y = d[row] - dmax;
    bfac[row] = (_Float16)__expf(y);
    dfac[row] = (_Float16)__expf(0.2f * y);
}

// ---------------------------------------------------------------------------
// Kernel 3 (main): 2048 blocks = 128 row-tiles(64 rows) x 16 j-splits,
// 6 blocks/CU resident (24 waves/CU). 1 A-frag/wave (16 rows), 2 B-buffers,
// R6 2-barrier scheme with vmcnt(2) cross-barrier prefetch. Bit-mask in
// VGPRs, separable factors, no exp, B shared by all 4 waves.
// ---------------------------------------------------------------------------
__global__ __launch_bounds__(256, 6) void k_main(const unsigned char* __restrict__ mask2,
                                                 const _Float16* __restrict__ WhT,
                                                 const _Float16* __restrict__ afac,
                                                 const _Float16* __restrict__ cfac,
                                                 const _Float16* __restrict__ bfac,
                                                 const _Float16* __restrict__ dfac,
                                                 float* __restrict__ part)
{
    __shared__ __align__(16) unsigned char sm[LDS_SZ];

    const int tid  = threadIdx.x;
    const int wv   = tid >> 6;
    const int lane = tid & 63;
    const int mrow = lane & 15;
    const int g    = lane >> 4;
    const int rt   = blockIdx.x & 127;
    const int js   = blockIdx.x >> 7;
    const int i0   = rt * 64;
    const int j0base = js * JRANGE;
    const int arow = i0 + wv * 16 + mrow;

    // ---- per-lane bit-mask: uint2 per cc, straight to VGPRs
    uint2 mw[2];
    {
        const unsigned char* mb = mask2 + (size_t)arow * 1024 + js * 64 + g * 8;
        mw[0] = *(const uint2*)(mb);
        mw[1] = *(const uint2*)(mb + 32);
    }

    // ---- per-row factors (packed fp16 pairs)
    half2v a2, c2;
    {
        union { _Float16 h[2]; half2v v; } u;
        u.h[0] = afac[arow]; u.h[1] = u.h[0]; a2 = u.v;
        u.h[0] = cfac[arow]; u.h[1] = u.h[0]; c2 = u.v;
    }

    f32x4 acc[5];
    #pragma unroll
    for (int n = 0; n < 5; ++n) acc[n] = (f32x4){0.f, 0.f, 0.f, 0.f};

    // stage B tile for iter it into buffer it&1: 2 async16/wave (swizzled)
    auto stageB = [&](int it) {
        const int j0 = j0base + it * JT;
        unsigned char* base = &sm[B_OFF + (it & 1) * 8192];
        #pragma unroll
        for (int qq = 0; qq < 2; ++qq) {
            const int q  = wv * 2 + qq;
            const int f  = q * 8 + (lane >> 3);
            const int sw = (lane & 7) ^ (lane >> 3);
            async16(WhT + (size_t)f * NN + j0 + sw * 8,
                    base + q * 1024 + lane * 16);
        }
    };

    {   // factor window: exactly 1 async16 per wave (uniform vmcnt count)
        const _Float16* fsrc = (wv == 0) ? (bfac + j0base + lane * 8)
                             : (wv == 1) ? (dfac + j0base + lane * 8)
                             : (wv == 2) ? (bfac + j0base + lane * 8)
                                         : (dfac + j0base + lane * 8);
        const int dst = (wv == 0) ? 0 : (wv == 1) ? 1024 : 2048 + (wv - 2) * 1024;
        async16(fsrc, &sm[FAC_OFF + dst + lane * 16]);
    }
    stageB(0);

    const half8 ones = {(_Float16)1.f, (_Float16)1.f, (_Float16)1.f, (_Float16)1.f,
                        (_Float16)1.f, (_Float16)1.f, (_Float16)1.f, (_Float16)1.f};
    const int r7 = mrow & 7;
    const int qh = mrow >> 3;

    #pragma unroll
    for (int it = 0; it < NIT; ++it) {
        if (it + 1 < NIT) {
            stageB(it + 1);                                   // prefetch
            asm volatile("s_waitcnt vmcnt(2)" ::: "memory");  // tile(it) landed
        } else {
            asm volatile("s_waitcnt vmcnt(0)" ::: "memory");
        }
        __builtin_amdgcn_s_barrier();                          // tile(it) visible
        asm volatile("" ::: "memory");

        const unsigned char* bb = &sm[B_OFF + (it & 1) * 8192];

        #pragma unroll
        for (int cc = 0; cc < 2; ++cc) {
            const unsigned word = (it < 4) ? mw[cc].x : mw[cc].y;
            const unsigned bt   = (word >> ((it & 3) * 8)) & 0xffu;

            const int colb = (it * 64 + cc * 32 + g * 8) * 2;
            uint4 bv4 = *(const uint4*)&sm[FAC_OFF + colb];
            uint4 dv4 = *(const uint4*)&sm[FAC_OFF + 1024 + colb];

            union { unsigned u[4]; half8 h; } af;
            #pragma unroll
            for (int k = 0; k < 4; ++k) {
                union { unsigned u; half2v v; } b2, d2, pm;
                b2.u = (&bv4.x)[k];
                d2.u = (&dv4.x)[k];
                pm.v = __builtin_elementwise_max(a2 * b2.v, c2 * d2.v);
                const unsigned lo = ((bt >> (2 * k)) & 1u) * 0xFFFFu;
                const unsigned hi = ((bt >> (2 * k + 1)) & 1u) * 0xFFFF0000u;
                af.u[k] = pm.u & (lo | hi);
            }

            #pragma unroll
            for (int n = 0; n < 4; ++n) {
                const int q = n * 2 + qh;
                half8 B = *(const half8*)&bb[q * 1024 + r7 * 128 +
                                             (((cc * 4 + g) ^ r7) * 16)];
                acc[n] = __builtin_amdgcn_mfma_f32_16x16x32_f16(af.h, B, acc[n], 0, 0, 0);
            }
            acc[4] = __builtin_amdgcn_mfma_f32_16x16x32_f16(af.h, ones, acc[4], 0, 0, 0);
        }

        asm volatile("" ::: "memory");
        __builtin_amdgcn_s_barrier();    // reads of buf done before overwrite
    }

    // ---- epilogue ----
    float* pb = part + (size_t)blockIdx.x * (64 * PROW) + wv * 16 * PROW;
    #pragma unroll
    for (int n = 0; n < 4; ++n)
        #pragma unroll
        for (int r = 0; r < 4; ++r)
            pb[(g * 4 + r) * PROW + n * 16 + mrow] = acc[n][r];
    if (mrow == 0) {
        #pragma unroll
        for (int r = 0; r < 4; ++r)
            pb[(g * 4 + r) * PROW + 64] = acc[4][r];
    }
}

// ---------------------------------------------------------------------------
// Kernel 4: combine 16 j-split partials, divide by l, ELU, write out.
// ---------------------------------------------------------------------------
__global__ __launch_bounds__(256) void k_reduce(const float* __restrict__ part,
                                                float* __restrict__ out)
{
    const int rb  = blockIdx.x;
    const int col = threadIdx.x & 63;
    const int r0  = threadIdx.x >> 6;
    #pragma unroll
    for (int rr = 0; rr < 4; ++rr) {
        const int r   = rb * 16 + r0 * 4 + rr;
        const int rtr = r >> 6;
        const int rl  = r & 63;
        float h = 0.f, l = 0.f;
        #pragma unroll
        for (int js = 0; js < JSPLIT; ++js) {
            const float* pbase =
                part + ((size_t)(js * 128 + rtr) * 64 + rl) * PROW;
            h += pbase[col];
            l += pbase[64];
        }
        float v = h / l;
        out[(size_t)r * FF + col] = (v > 0.f) ? v : (__expf(v) - 1.0f);
    }
}

extern "C" void kernel_launch(void* const* d_in, const int* in_sizes, int n_in,
                              void* d_out, int out_size, void* d_ws, size_t ws_size,
                              hipStream_t stream)
{
    const float* inp = (const float*)d_in[0];
    const int*   adj = (const int*)d_in[1];
    const float* W   = (const float*)d_in[2];
    const float* a   = (const float*)d_in[3];
    float* out = (float*)d_out;

    char* ws = (char*)d_ws;
    _Float16* WhT = (_Float16*)ws;                          // 80*NN*2 reserved
    float* s    = (float*)(ws + (size_t)80 * NN * 2);
    float* d    = s + NN;
    float* dmp  = d + NN;
    _Float16* afac = (_Float16*)(dmp + 512);
    _Float16* cfac = afac + NN;
    _Float16* bfac = cfac + NN;
    _Float16* dfac = bfac + NN;
    float* part = (float*)(dfac + NN);                      // 2048*64*66*4 = 34.6 MB
    unsigned char* mask2 = (unsigned char*)(part + (size_t)2048 * 64 * PROW);  // 8 MB

    k_pack  <<<NN / 2, 256, 0, stream>>>(adj, mask2);
    k_prep  <<<NN / 16, 256, 0, stream>>>(inp, W, a, WhT, s, d, dmp);
    k_vec   <<<NN / 256, 256, 0, stream>>>(s, d, dmp, afac, cfac, bfac, dfac);
    k_main  <<<128 * JSPLIT, 256, 0, stream>>>(mask2, WhT, afac, cfac, bfac, dfac, part);
    k_reduce<<<NN / 16, 256, 0, stream>>>(part, out);
}